// Round 5
// baseline (883.001 us; speedup 1.0000x reference)
//
#include <hip/hip_runtime.h>
#include <hip/hip_bf16.h>
#include <stdint.h>

typedef __bf16 bf16;
typedef bf16 bf16x8 __attribute__((ext_vector_type(8)));
typedef bf16 bf16x4 __attribute__((ext_vector_type(4)));
typedef float f32x4 __attribute__((ext_vector_type(4)));

#define N_TOK 8192
#define D_MODEL 1024
#define H_R 512
#define N_EXP 6
#define F_FF 1536
#define FLAG_CAP 1024

// Abramowitz-Stegun 7.1.26: |err| <= 1.5e-7
__device__ __forceinline__ float erf_fast(float x) {
    float ax = fabsf(x);
    float t = 1.0f / (1.0f + 0.3275911f * ax);
    float p = t * (0.254829592f + t * (-0.284496736f + t * (1.421413741f +
              t * (-1.453152027f + t * 1.061405429f))));
    float r = 1.0f - p * __expf(-ax * ax);
    return copysignf(r, x);
}
__device__ __forceinline__ float gelu_f(float x) {
    return 0.5f * x * (1.0f + erf_fast(x * 0.70710678118654752f));
}
__device__ __forceinline__ float silu_f(float x) {
    return x * (1.0f / (1.0f + __expf(-x)));
}

typedef __attribute__((address_space(1))) const void* gas1;
typedef __attribute__((address_space(3))) void* las3;

__device__ __forceinline__ void gload16(const void* g, void* l) {
    __builtin_amdgcn_global_load_lds((gas1)g, (las3)l, 16, 0, 0);
}

// LDS chunk swizzle: row r's logical 16B chunk q lives at chunk-slot (q + (r>>1)) & 3.
// Slot c (LDS order) must fetch global chunk ((c&3) - ((c>>2)>>1)) & 3 of local row c>>2.
__device__ __forceinline__ int swz_src_q(int c) {
    return (((c & 3) - ((c >> 2) >> 1)) & 3);
}

// ---------------- conversion / transpose ------------------------------------

__global__ __launch_bounds__(256) void convert_x_split(
    const float* __restrict__ x, bf16* __restrict__ xh, bf16* __restrict__ xl) {
    size_t i = ((size_t)blockIdx.x * 256 + threadIdx.x) * 8;
    f32x4 a = *(const f32x4*)(x + i);
    f32x4 b = *(const f32x4*)(x + i + 4);
    float v[8] = {a[0], a[1], a[2], a[3], b[0], b[1], b[2], b[3]};
    bf16x8 vh, vl;
    #pragma unroll
    for (int k = 0; k < 8; ++k) {
        bf16 h = (bf16)v[k];
        vh[k] = h;
        vl[k] = (bf16)(v[k] - (float)h);
    }
    *(bf16x8*)(xh + i) = vh;
    *(bf16x8*)(xl + i) = vl;
}

__global__ __launch_bounds__(256) void transpose_bf16_64(
    const float* __restrict__ in, bf16* __restrict__ out, int R, int C) {
    __shared__ float tile[64][65];
    const float* inp = in + (size_t)blockIdx.z * R * C;
    bf16* op = out + (size_t)blockIdx.z * R * C;
    int tx = threadIdx.x & 15, ty = threadIdx.x >> 4;
    int r0 = blockIdx.y * 64, c0 = blockIdx.x * 64;
    #pragma unroll
    for (int p = 0; p < 4; ++p) {
        int row = p * 16 + ty;
        f32x4 v = *(const f32x4*)(inp + (size_t)(r0 + row) * C + c0 + tx * 4);
        tile[row][tx * 4 + 0] = v[0];
        tile[row][tx * 4 + 1] = v[1];
        tile[row][tx * 4 + 2] = v[2];
        tile[row][tx * 4 + 3] = v[3];
    }
    __syncthreads();
    #pragma unroll
    for (int p = 0; p < 4; ++p) {
        int cc = p * 16 + ty;
        bf16x4 o;
        #pragma unroll
        for (int k = 0; k < 4; ++k) o[k] = (bf16)tile[tx * 4 + k][cc];
        *(bf16x4*)(op + (size_t)(c0 + cc) * R + r0 + tx * 4) = o;
    }
}

__global__ __launch_bounds__(256) void transpose_split(
    const float* __restrict__ in, bf16* __restrict__ oh, bf16* __restrict__ ol,
    int R, int C) {
    __shared__ float tile[32][33];
    int tx = threadIdx.x & 31, ty = threadIdx.x >> 5;
    int r0 = blockIdx.y * 32, c0 = blockIdx.x * 32;
    #pragma unroll
    for (int yy = ty; yy < 32; yy += 8)
        tile[yy][tx] = in[(size_t)(r0 + yy) * C + c0 + tx];
    __syncthreads();
    #pragma unroll
    for (int yy = ty; yy < 32; yy += 8) {
        float v = tile[tx][yy];
        bf16 h = (bf16)v;
        size_t o = (size_t)(c0 + yy) * R + r0 + tx;
        oh[o] = h;
        ol[o] = (bf16)(v - (float)h);
    }
}

// ---------------- 128x128 bf16 MFMA GEMM core (async staging, swizzled LDS) --

struct SMemStd {
    alignas(16) bf16 As[128 * 32];
    alignas(16) bf16 Bs[128 * 32];
};

__device__ __forceinline__ void gemm_core_async(
    const bf16* gA0, const bf16* gA1, const bf16* gB0, const bf16* gB1,
    int K, bf16* As, bf16* Bs, f32x4 acc[4][4]) {
    const int tid = threadIdx.x;
    const int lane = tid & 63;
    const int w = tid >> 6;
    const int wm = w & 1, wn = w >> 1;
    const int lc = lane & 15;
    // swizzled fragment chunk offset: constant per thread, conflict-free (2-way)
    const int koff = ((((lane >> 4) + (lc >> 1)) & 3) * 8);
    bf16* lA0 = As + w * 512;          // slot c = tid
    bf16* lA1 = As + 2048 + w * 512;   // slot c = tid + 256
    bf16* lB0 = Bs + w * 512;
    bf16* lB1 = Bs + 2048 + w * 512;
    for (int kb = 0; kb < K; kb += 32) {
        __syncthreads();
        gload16(gA0 + kb, lA0);
        gload16(gA1 + kb, lA1);
        gload16(gB0 + kb, lB0);
        gload16(gB1 + kb, lB1);
        __syncthreads();
        bf16x8 af[4], bfr[4];
        #pragma unroll
        for (int i = 0; i < 4; ++i)
            af[i] = *(const bf16x8*)(As + (wm * 64 + i * 16 + lc) * 32 + koff);
        #pragma unroll
        for (int j = 0; j < 4; ++j)
            bfr[j] = *(const bf16x8*)(Bs + (wn * 64 + j * 16 + lc) * 32 + koff);
        #pragma unroll
        for (int i = 0; i < 4; ++i)
            #pragma unroll
            for (int j = 0; j < 4; ++j)
                acc[i][j] = __builtin_amdgcn_mfma_f32_16x16x32_bf16(af[i], bfr[j], acc[i][j], 0, 0, 0);
    }
}

// ---------------- router GEMM1: z-split 3-term (fp32-accurate sum) ----------
// grid (y=64, n=4, z=3), y fastest for B-panel L2 residency

__global__ __launch_bounds__(256) void router_gemm1_3(
    const bf16* __restrict__ xh, const bf16* __restrict__ xl,
    const bf16* __restrict__ wTh, const bf16* __restrict__ wTl,
    float* __restrict__ hp0, float* __restrict__ hp1, float* __restrict__ hp2) {
    __shared__ SMemStd sm;
    const int z = blockIdx.z;
    const bf16* Ab = (z == 2) ? xl : xh;
    const bf16* Bb = (z == 1) ? wTl : wTh;
    float* hp = (z == 0) ? hp0 : (z == 1 ? hp1 : hp2);
    const int tid = threadIdx.x;
    const int mbase = blockIdx.x * 128, nbase = blockIdx.y * 128;
    int c0 = tid, c1 = tid + 256;
    const bf16* gA0 = Ab + (size_t)(mbase + (c0 >> 2)) * D_MODEL + swz_src_q(c0) * 8;
    const bf16* gA1 = Ab + (size_t)(mbase + (c1 >> 2)) * D_MODEL + swz_src_q(c1) * 8;
    const bf16* Bt = Bb + (size_t)nbase * D_MODEL;
    const bf16* gB0 = Bt + (size_t)(c0 >> 2) * D_MODEL + swz_src_q(c0) * 8;
    const bf16* gB1 = Bt + (size_t)(c1 >> 2) * D_MODEL + swz_src_q(c1) * 8;
    f32x4 acc[4][4] = {};
    gemm_core_async(gA0, gA1, gB0, gB1, D_MODEL, sm.As, sm.Bs, acc);
    const int lane = tid & 63;
    const int w = tid >> 6;
    const int wm = w & 1, wn = w >> 1;
    const int lc = lane & 15, quad = lane >> 4;
    #pragma unroll
    for (int i = 0; i < 4; ++i)
        #pragma unroll
        for (int j = 0; j < 4; ++j) {
            int col = nbase + wn * 64 + j * 16 + lc;
            #pragma unroll
            for (int r = 0; r < 4; ++r) {
                int row = mbase + wm * 64 + i * 16 + quad * 4 + r;
                hp[(size_t)row * H_R + col] = acc[i][j][r];
            }
        }
}

// ---------------- fused LayerNorm + GELU + logits + top-2 + counts ----------

// meta: [0..7] counts, [8..15] offsets, [16..23] cursor, [24] nflag
__global__ __launch_bounds__(256) void ln_router2(
    const float* __restrict__ hp0, const float* __restrict__ hp1,
    const float* __restrict__ hp2, const float* __restrict__ r1b,
    const float* __restrict__ g, const float* __restrict__ bta,
    const float* __restrict__ r2w, const float* __restrict__ r2b,
    const float* __restrict__ temp, const float* __restrict__ rbias,
    int* __restrict__ top_i, float* __restrict__ top_p,
    int* __restrict__ flaglist, int* __restrict__ meta) {
    __shared__ float Wl[H_R * N_EXP];
    int tid = threadIdx.x;
    for (int i = tid; i < H_R * N_EXP; i += 256) Wl[i] = r2w[i];
    __syncthreads();
    int w = tid >> 6, lane = tid & 63;
    int t = blockIdx.x * 4 + w;
    size_t rbase = (size_t)t * H_R;
    int k0 = lane * 8;
    float v[8];
    {
        f32x4 a0 = *(const f32x4*)(hp0 + rbase + k0);
        f32x4 a1 = *(const f32x4*)(hp0 + rbase + k0 + 4);
        f32x4 b0 = *(const f32x4*)(hp1 + rbase + k0);
        f32x4 b1 = *(const f32x4*)(hp1 + rbase + k0 + 4);
        f32x4 c0 = *(const f32x4*)(hp2 + rbase + k0);
        f32x4 c1 = *(const f32x4*)(hp2 + rbase + k0 + 4);
        f32x4 d0 = *(const f32x4*)(r1b + k0);
        f32x4 d1 = *(const f32x4*)(r1b + k0 + 4);
        #pragma unroll
        for (int k = 0; k < 4; ++k) {
            v[k]     = a0[k] + b0[k] + c0[k] + d0[k];
            v[k + 4] = a1[k] + b1[k] + c1[k] + d1[k];
        }
    }
    float s = 0.f;
    #pragma unroll
    for (int k = 0; k < 8; ++k) s += v[k];
    #pragma unroll
    for (int off = 32; off; off >>= 1) s += __shfl_xor(s, off);
    float mu = s * (1.0f / H_R);
    float q = 0.f;
    #pragma unroll
    for (int k = 0; k < 8; ++k) { float d = v[k] - mu; q += d * d; }
    #pragma unroll
    for (int off = 32; off; off >>= 1) q += __shfl_xor(q, off);
    float scl = 1.0f / sqrtf(q * (1.0f / H_R) + 1e-5f);
    f32x4 g0 = *(const f32x4*)(g + k0), g1 = *(const f32x4*)(g + k0 + 4);
    f32x4 b0 = *(const f32x4*)(bta + k0), b1v = *(const f32x4*)(bta + k0 + 4);
    float G[8] = {g0[0], g0[1], g0[2], g0[3], g1[0], g1[1], g1[2], g1[3]};
    float B[8] = {b0[0], b0[1], b0[2], b0[3], b1v[0], b1v[1], b1v[2], b1v[3]};
    float acc[N_EXP] = {};
    #pragma unroll
    for (int k = 0; k < 8; ++k) {
        float y = gelu_f((v[k] - mu) * scl * G[k] + B[k]);
        const float* wr = &Wl[(k0 + k) * N_EXP];
        #pragma unroll
        for (int e = 0; e < N_EXP; ++e) acc[e] += y * wr[e];
    }
    #pragma unroll
    for (int e = 0; e < N_EXP; ++e)
        #pragma unroll
        for (int off = 32; off; off >>= 1) acc[e] += __shfl_xor(acc[e], off);
    if (lane == 0) {
        float tinv = 1.0f / temp[0];
        float lg[N_EXP];
        #pragma unroll
        for (int e = 0; e < N_EXP; ++e) lg[e] = (acc[e] + r2b[e]) * tinv + rbias[e];
        float v1 = -1e30f; int i1 = 0;
        #pragma unroll
        for (int e = 0; e < N_EXP; ++e) if (lg[e] > v1) { v1 = lg[e]; i1 = e; }
        float v2 = -1e30f; int i2 = 0;
        #pragma unroll
        for (int e = 0; e < N_EXP; ++e) if (e != i1 && lg[e] > v2) { v2 = lg[e]; i2 = e; }
        float v3 = -1e30f;
        #pragma unroll
        for (int e = 0; e < N_EXP; ++e) if (e != i1 && e != i2 && lg[e] > v3) v3 = lg[e];
        float ssum = 0.f;
        #pragma unroll
        for (int e = 0; e < N_EXP; ++e) ssum += __expf(lg[e] - v1);
        float inv = 1.0f / ssum;
        top_i[2 * t] = i1; top_i[2 * t + 1] = i2;
        top_p[2 * t] = inv;
        top_p[2 * t + 1] = __expf(v2 - v1) * inv;
        atomicAdd(&meta[i1], 1);
        atomicAdd(&meta[i2], 1);
        if (v2 - v3 < 1e-3f) {
            int ix = atomicAdd(&meta[24], 1);
            if (ix < FLAG_CAP) flaglist[ix] = t;
        }
    }
}

// ---------------- fp64 exact rescue (also fixes counts) ---------------------

__global__ __launch_bounds__(256) void router_rescue(
    const float* __restrict__ x, const float* __restrict__ r1w,
    const float* __restrict__ r1b, const float* __restrict__ lng,
    const float* __restrict__ lnb, const float* __restrict__ r2w,
    const float* __restrict__ r2b, const float* __restrict__ temp,
    const float* __restrict__ rbias, const int* __restrict__ flaglist,
    int* __restrict__ meta, int* __restrict__ top_i, float* __restrict__ top_p) {
    int n = meta[24]; if (n > FLAG_CAP) n = FLAG_CAP;
    if ((int)blockIdx.x >= n) return;
    int t = flaglist[blockIdx.x];
    __shared__ double xs[D_MODEL];
    __shared__ double hbuf[H_R];
    __shared__ double red[8];
    int tid = threadIdx.x;
    for (int k = tid; k < D_MODEL; k += 256) xs[k] = (double)x[(size_t)t * D_MODEL + k];
    __syncthreads();
    for (int c = tid; c < H_R; c += 256) {
        double s = 0.0;
        for (int k = 0; k < D_MODEL; ++k) s += xs[k] * (double)r1w[(size_t)k * H_R + c];
        hbuf[c] = s + (double)r1b[c];
    }
    __syncthreads();
    double ls = 0.0;
    for (int c = tid; c < H_R; c += 256) ls += hbuf[c];
    #pragma unroll
    for (int off = 32; off; off >>= 1) ls += __shfl_xor(ls, off);
    if ((tid & 63) == 0) red[tid >> 6] = ls;
    __syncthreads();
    double mu = (red[0] + red[1] + red[2] + red[3]) * (1.0 / H_R);
    __syncthreads();
    double q = 0.0;
    for (int c = tid; c < H_R; c += 256) { double d = hbuf[c] - mu; q += d * d; }
    #pragma unroll
    for (int off = 32; off; off >>= 1) q += __shfl_xor(q, off);
    if ((tid & 63) == 0) red[tid >> 6] = q;
    __syncthreads();
    double var = (red[0] + red[1] + red[2] + red[3]) * (1.0 / H_R);
    double scl = 1.0 / sqrt(var + 1e-5);
    __syncthreads();
    for (int c = tid; c < H_R; c += 256) {
        double y = (hbuf[c] - mu) * scl * (double)lng[c] + (double)lnb[c];
        hbuf[c] = 0.5 * y * (1.0 + erf(y * 0.70710678118654752440));
    }
    __syncthreads();
    if (tid < N_EXP) {
        double s = 0.0;
        for (int k = 0; k < H_R; ++k) s += hbuf[k] * (double)r2w[k * N_EXP + tid];
        red[tid] = (s + (double)r2b[tid]) / (double)temp[0] + (double)rbias[tid];
    }
    __syncthreads();
    if (tid == 0) {
        double lg[N_EXP];
        #pragma unroll
        for (int e = 0; e < N_EXP; ++e) lg[e] = red[e];
        double v1 = -1e300; int i1 = 0;
        for (int e = 0; e < N_EXP; ++e) if (lg[e] > v1) { v1 = lg[e]; i1 = e; }
        double v2 = -1e300; int i2 = 0;
        for (int e = 0; e < N_EXP; ++e) if (e != i1 && lg[e] > v2) { v2 = lg[e]; i2 = e; }
        double s = 0.0;
        for (int e = 0; e < N_EXP; ++e) s += exp(lg[e] - v1);
        double inv = 1.0 / s;
        int o1 = top_i[2 * t], o2 = top_i[2 * t + 1];
        if (o1 != i1 || o2 != i2) {
            atomicSub(&meta[o1], 1); atomicSub(&meta[o2], 1);
            atomicAdd(&meta[i1], 1); atomicAdd(&meta[i2], 1);
        }
        top_i[2 * t] = i1; top_i[2 * t + 1] = i2;
        top_p[2 * t] = (float)inv;
        top_p[2 * t + 1] = (float)(exp(v2 - v1) * inv);
    }
}

// ---------------- scan / scatter --------------------------------------------

__global__ void scan_kernel(int* __restrict__ meta) {
    if (threadIdx.x == 0) {
        int o = 0;
        for (int e = 0; e < N_EXP; ++e) { meta[8 + e] = o; o += meta[e]; }
    }
}

__global__ __launch_bounds__(256) void scatter_kernel(
    const int* __restrict__ top_i, int* __restrict__ meta,
    int* __restrict__ atok, int* __restrict__ ainv) {
    int t = blockIdx.x * 256 + threadIdx.x;
    #pragma unroll
    for (int j = 0; j < 2; ++j) {
        int e = top_i[2 * t + j];
        int pos = atomicAdd(&meta[16 + e], 1);
        int a = meta[8 + e] + pos;
        atok[a] = t;
        ainv[2 * t + j] = a;
    }
}

// ---------------- expert GEMMs (grid: y fastest, then n, then e) ------------

__global__ __launch_bounds__(256) void expert_gemm1(
    const bf16* __restrict__ xb, const bf16* __restrict__ W1T,
    const float* __restrict__ b1, const int* __restrict__ meta,
    const int* __restrict__ atok, bf16* __restrict__ act) {
    int e = blockIdx.z;
    int rows = meta[e];
    int mloc = blockIdx.x * 128;
    if (mloc >= rows) return;
    int base = meta[8 + e];
    __shared__ SMemStd sm;
    int tid = threadIdx.x;
    int nbase = blockIdx.y * 128;
    int c0 = tid, c1 = tid + 256;
    int r0 = mloc + (c0 >> 2); if (r0 > rows - 1) r0 = rows - 1;
    int r1 = mloc + (c1 >> 2); if (r1 > rows - 1) r1 = rows - 1;
    const bf16* gA0 = xb + (size_t)atok[base + r0] * D_MODEL + swz_src_q(c0) * 8;
    const bf16* gA1 = xb + (size_t)atok[base + r1] * D_MODEL + swz_src_q(c1) * 8;
    const bf16* Bt = W1T + ((size_t)e * F_FF + nbase) * D_MODEL;
    const bf16* gB0 = Bt + (size_t)(c0 >> 2) * D_MODEL + swz_src_q(c0) * 8;
    const bf16* gB1 = Bt + (size_t)(c1 >> 2) * D_MODEL + swz_src_q(c1) * 8;
    f32x4 acc[4][4] = {};
    gemm_core_async(gA0, gA1, gB0, gB1, D_MODEL, sm.As, sm.Bs, acc);
    const int lane = tid & 63;
    const int w = tid >> 6;
    const int wm = w & 1, wn = w >> 1;
    const int lc = lane & 15, quad = lane >> 4;
    bool odd = (e & 1) != 0;
    #pragma unroll
    for (int i = 0; i < 4; ++i)
        #pragma unroll
        for (int j = 0; j < 4; ++j) {
            int col = nbase + wn * 64 + j * 16 + lc;
            float bias = b1[e * F_FF + col];
            #pragma unroll
            for (int r = 0; r < 4; ++r) {
                int rloc = mloc + wm * 64 + i * 16 + quad * 4 + r;
                if (rloc < rows) {
                    float vv = acc[i][j][r] + bias;
                    vv = odd ? silu_f(vv) : gelu_f(vv);
                    act[(size_t)(base + rloc) * F_FF + col] = (bf16)vv;
                }
            }
        }
}

__global__ __launch_bounds__(256) void expert_gemm2(
    const bf16* __restrict__ act, const bf16* __restrict__ W2T,
    const float* __restrict__ b2, const int* __restrict__ meta,
    float* __restrict__ eo) {
    int e = blockIdx.z;
    int rows = meta[e];
    int mloc = blockIdx.x * 128;
    if (mloc >= rows) return;
    int base = meta[8 + e];
    __shared__ SMemStd sm;
    int tid = threadIdx.x;
    int nbase = blockIdx.y * 128;
    int c0 = tid, c1 = tid + 256;
    int r0 = mloc + (c0 >> 2); if (r0 > rows - 1) r0 = rows - 1;
    int r1 = mloc + (c1 >> 2); if (r1 > rows - 1) r1 = rows - 1;
    const bf16* gA0 = act + (size_t)(base + r0) * F_FF + swz_src_q(c0) * 8;
    const bf16* gA1 = act + (size_t)(base + r1) * F_FF + swz_src_q(c1) * 8;
    const bf16* Bt = W2T + ((size_t)e * D_MODEL + nbase) * F_FF;
    const bf16* gB0 = Bt + (size_t)(c0 >> 2) * F_FF + swz_src_q(c0) * 8;
    const bf16* gB1 = Bt + (size_t)(c1 >> 2) * F_FF + swz_src_q(c1) * 8;
    f32x4 acc[4][4] = {};
    gemm_core_async(gA0, gA1, gB0, gB1, F_FF, sm.As, sm.Bs, acc);
    const int lane = tid & 63;
    const int w = tid >> 6;
    const int wm = w & 1, wn = w >> 1;
    const int lc = lane & 15, quad = lane >> 4;
    #pragma unroll
    for (int i = 0; i < 4; ++i)
        #pragma unroll
        for (int j = 0; j < 4; ++j) {
            int col = nbase + wn * 64 + j * 16 + lc;
            float bias = b2[e * D_MODEL + col];
            #pragma unroll
            for (int r = 0; r < 4; ++r) {
                int rloc = mloc + wm * 64 + i * 16 + quad * 4 + r;
                if (rloc < rows)
                    eo[(size_t)(base + rloc) * D_MODEL + col] = acc[i][j][r] + bias;
            }
        }
}

// ---------------- weighted combine ------------------------------------------

__global__ __launch_bounds__(256) void combine_kernel(
    const float* __restrict__ eo, const int* __restrict__ ainv,
    const float* __restrict__ top_p, float* __restrict__ out) {
    int t = blockIdx.x;
    int s0 = ainv[2 * t], s1 = ainv[2 * t + 1];
    float p0 = top_p[2 * t], p1 = top_p[2 * t + 1];
    int c = threadIdx.x * 4;
    f32x4 a = *(const f32x4*)(eo + (size_t)s0 * D_MODEL + c);
    f32x4 b = *(const f32x4*)(eo + (size_t)s1 * D_MODEL + c);
    f32x4 o;
    #pragma unroll
    for (int k = 0; k < 4; ++k) o[k] = a[k] * p0 + b[k] * p1;
    *(f32x4*)(out + (size_t)t * D_MODEL + c) = o;
}

// ---------------- launch ----------------------------------------------------

extern "C" void kernel_launch(void* const* d_in, const int* in_sizes, int n_in,
                              void* d_out, int out_size, void* d_ws, size_t ws_size,
                              hipStream_t stream) {
    const float* x     = (const float*)d_in[0];
    const float* r1w   = (const float*)d_in[1];
    const float* r1b   = (const float*)d_in[2];
    const float* lng   = (const float*)d_in[3];
    const float* lnb   = (const float*)d_in[4];
    const float* r2w   = (const float*)d_in[5];
    const float* r2b   = (const float*)d_in[6];
    const float* temp  = (const float*)d_in[7];
    const float* rbias = (const float*)d_in[8];
    const float* W1    = (const float*)d_in[9];
    const float* b1    = (const float*)d_in[10];
    const float* W2    = (const float*)d_in[11];
    const float* b2    = (const float*)d_in[12];
    float* out = (float*)d_out;

    char* ws = (char*)d_ws;
    size_t off = 0;
    auto alloc = [&](size_t bytes) -> void* {
        void* p = ws + off;
        off = (off + bytes + 255) & ~(size_t)255;
        return p;
    };
    bf16*  xh    = (bf16*)alloc((size_t)N_TOK * D_MODEL * 2);
    bf16*  xl    = (bf16*)alloc((size_t)N_TOK * D_MODEL * 2);
    bf16*  r1wTh = (bf16*)alloc((size_t)H_R * D_MODEL * 2);
    bf16*  r1wTl = (bf16*)alloc((size_t)H_R * D_MODEL * 2);
    bf16*  W1T   = (bf16*)alloc((size_t)N_EXP * F_FF * D_MODEL * 2);
    bf16*  W2T   = (bf16*)alloc((size_t)N_EXP * D_MODEL * F_FF * 2);
    float* hp0   = (float*)alloc((size_t)N_TOK * H_R * 4);
    int*   top_i = (int*)alloc((size_t)N_TOK * 2 * 4);
    float* top_p = (float*)alloc((size_t)N_TOK * 2 * 4);
    int*   meta  = (int*)alloc(256);
    int*   flags = (int*)alloc(FLAG_CAP * 4);
    int*   atok  = (int*)alloc((size_t)2 * N_TOK * 4);
    int*   ainv  = (int*)alloc((size_t)2 * N_TOK * 4);
    bf16*  actb  = (bf16*)alloc((size_t)2 * N_TOK * F_FF * 2);
    float* eo    = (float*)alloc((size_t)2 * N_TOK * D_MODEL * 4);
    float* hp1 = (float*)actb;
    float* hp2 = (float*)((char*)actb + (size_t)N_TOK * H_R * 4);
    (void)ws_size; (void)n_in; (void)in_sizes;

    hipMemsetAsync(meta, 0, 256, stream);

    convert_x_split<<<(N_TOK * D_MODEL) / (256 * 8), 256, 0, stream>>>(x, xh, xl);
    transpose_split<<<dim3(H_R / 32, D_MODEL / 32, 1), 256, 0, stream>>>(
        r1w, r1wTh, r1wTl, D_MODEL, H_R);
    transpose_bf16_64<<<dim3(F_FF / 64, D_MODEL / 64, N_EXP), 256, 0, stream>>>(
        W1, W1T, D_MODEL, F_FF);
    transpose_bf16_64<<<dim3(D_MODEL / 64, F_FF / 64, N_EXP), 256, 0, stream>>>(
        W2, W2T, F_FF, D_MODEL);

    router_gemm1_3<<<dim3(N_TOK / 128, H_R / 128, 3), 256, 0, stream>>>(
        xh, xl, r1wTh, r1wTl, hp0, hp1, hp2);
    ln_router2<<<N_TOK / 4, 256, 0, stream>>>(
        hp0, hp1, hp2, r1b, lng, lnb, r2w, r2b, temp, rbias, top_i, top_p, flags, meta);
    router_rescue<<<FLAG_CAP, 256, 0, stream>>>(
        x, r1w, r1b, lng, lnb, r2w, r2b, temp, rbias, flags, meta, top_i, top_p);
    scan_kernel<<<1, 64, 0, stream>>>(meta);
    scatter_kernel<<<N_TOK / 256, 256, 0, stream>>>(top_i, meta, atok, ainv);

    expert_gemm1<<<dim3(N_TOK / 128, F_FF / 128, N_EXP), 256, 0, stream>>>(
        xh, W1T, b1, meta, atok, actb);
    expert_gemm2<<<dim3(N_TOK / 128, D_MODEL / 128, N_EXP), 256, 0, stream>>>(
        actb, W2T, b2, meta, eo);
    combine_kernel<<<N_TOK, 256, 0, stream>>>(eo, ainv, top_p, out);
}

// Round 6
// 599.743 us; speedup vs baseline: 1.4723x; 1.4723x over previous
//
#include <hip/hip_runtime.h>
#include <hip/hip_bf16.h>
#include <stdint.h>

typedef __bf16 bf16;
typedef bf16 bf16x8 __attribute__((ext_vector_type(8)));
typedef bf16 bf16x4 __attribute__((ext_vector_type(4)));
typedef float f32x4 __attribute__((ext_vector_type(4)));
typedef int i32x4 __attribute__((ext_vector_type(4)));

#define N_TOK 8192
#define D_MODEL 1024
#define H_R 512
#define N_EXP 6
#define F_FF 1536
#define FLAG_CAP 1024

// Abramowitz-Stegun 7.1.26: |err| <= 1.5e-7
__device__ __forceinline__ float erf_fast(float x) {
    float ax = fabsf(x);
    float t = 1.0f / (1.0f + 0.3275911f * ax);
    float p = t * (0.254829592f + t * (-0.284496736f + t * (1.421413741f +
              t * (-1.453152027f + t * 1.061405429f))));
    float r = 1.0f - p * __expf(-ax * ax);
    return copysignf(r, x);
}
__device__ __forceinline__ float gelu_f(float x) {
    return 0.5f * x * (1.0f + erf_fast(x * 0.70710678118654752f));
}
__device__ __forceinline__ float silu_f(float x) {
    return x * (1.0f / (1.0f + __expf(-x)));
}

typedef __attribute__((address_space(1))) const void* gas1;
typedef __attribute__((address_space(3))) void* las3;

__device__ __forceinline__ void gload16(const void* g, void* l) {
    __builtin_amdgcn_global_load_lds((gas1)g, (las3)l, 16, 0, 0);
}

// LDS chunk swizzle: row r's logical 16B chunk q lives at chunk-slot (q + (r>>1)) & 3.
__device__ __forceinline__ int swz_src_q(int c) {
    return (((c & 3) - ((c >> 2) >> 1)) & 3);
}

// ---------------- conversion / transpose ------------------------------------

__global__ __launch_bounds__(256) void convert_x_split(
    const float* __restrict__ x, bf16* __restrict__ xh, bf16* __restrict__ xl) {
    size_t i = ((size_t)blockIdx.x * 256 + threadIdx.x) * 8;
    f32x4 a = *(const f32x4*)(x + i);
    f32x4 b = *(const f32x4*)(x + i + 4);
    float v[8] = {a[0], a[1], a[2], a[3], b[0], b[1], b[2], b[3]};
    bf16x8 vh, vl;
    #pragma unroll
    for (int k = 0; k < 8; ++k) {
        bf16 h = (bf16)v[k];
        vh[k] = h;
        vl[k] = (bf16)(v[k] - (float)h);
    }
    *(bf16x8*)(xh + i) = vh;
    *(bf16x8*)(xl + i) = vl;
}

__global__ __launch_bounds__(256) void transpose_bf16_64(
    const float* __restrict__ in, bf16* __restrict__ out, int R, int C) {
    __shared__ float tile[64][65];
    const float* inp = in + (size_t)blockIdx.z * R * C;
    bf16* op = out + (size_t)blockIdx.z * R * C;
    int tx = threadIdx.x & 15, ty = threadIdx.x >> 4;
    int r0 = blockIdx.y * 64, c0 = blockIdx.x * 64;
    #pragma unroll
    for (int p = 0; p < 4; ++p) {
        int row = p * 16 + ty;
        f32x4 v = *(const f32x4*)(inp + (size_t)(r0 + row) * C + c0 + tx * 4);
        tile[row][tx * 4 + 0] = v[0];
        tile[row][tx * 4 + 1] = v[1];
        tile[row][tx * 4 + 2] = v[2];
        tile[row][tx * 4 + 3] = v[3];
    }
    __syncthreads();
    #pragma unroll
    for (int p = 0; p < 4; ++p) {
        int cc = p * 16 + ty;
        bf16x4 o;
        #pragma unroll
        for (int k = 0; k < 4; ++k) o[k] = (bf16)tile[tx * 4 + k][cc];
        *(bf16x4*)(op + (size_t)(c0 + cc) * R + r0 + tx * 4) = o;
    }
}

__global__ __launch_bounds__(256) void transpose_split(
    const float* __restrict__ in, bf16* __restrict__ oh, bf16* __restrict__ ol,
    int R, int C) {
    __shared__ float tile[32][33];
    int tx = threadIdx.x & 31, ty = threadIdx.x >> 5;
    int r0 = blockIdx.y * 32, c0 = blockIdx.x * 32;
    #pragma unroll
    for (int yy = ty; yy < 32; yy += 8)
        tile[yy][tx] = in[(size_t)(r0 + yy) * C + c0 + tx];
    __syncthreads();
    #pragma unroll
    for (int yy = ty; yy < 32; yy += 8) {
        float v = tile[tx][yy];
        bf16 h = (bf16)v;
        size_t o = (size_t)(c0 + yy) * R + r0 + tx;
        oh[o] = h;
        ol[o] = (bf16)(v - (float)h);
    }
}

// ---------------- 128x128 bf16 MFMA GEMM core (async staging, swizzled LDS) --

struct SMemStd {
    alignas(16) bf16 As[128 * 32];
    alignas(16) bf16 Bs[128 * 32];
};

__device__ __forceinline__ void gemm_core_async(
    const bf16* gA0, const bf16* gA1, const bf16* gB0, const bf16* gB1,
    int K, bf16* As, bf16* Bs, f32x4 acc[4][4]) {
    const int tid = threadIdx.x;
    const int lane = tid & 63;
    const int w = tid >> 6;
    const int wm = w & 1, wn = w >> 1;
    const int lc = lane & 15;
    const int koff = ((((lane >> 4) + (lc >> 1)) & 3) * 8);
    bf16* lA0 = As + w * 512;
    bf16* lA1 = As + 2048 + w * 512;
    bf16* lB0 = Bs + w * 512;
    bf16* lB1 = Bs + 2048 + w * 512;
    for (int kb = 0; kb < K; kb += 32) {
        __syncthreads();
        gload16(gA0 + kb, lA0);
        gload16(gA1 + kb, lA1);
        gload16(gB0 + kb, lB0);
        gload16(gB1 + kb, lB1);
        __syncthreads();
        bf16x8 af[4], bfr[4];
        #pragma unroll
        for (int i = 0; i < 4; ++i)
            af[i] = *(const bf16x8*)(As + (wm * 64 + i * 16 + lc) * 32 + koff);
        #pragma unroll
        for (int j = 0; j < 4; ++j)
            bfr[j] = *(const bf16x8*)(Bs + (wn * 64 + j * 16 + lc) * 32 + koff);
        #pragma unroll
        for (int i = 0; i < 4; ++i)
            #pragma unroll
            for (int j = 0; j < 4; ++j)
                acc[i][j] = __builtin_amdgcn_mfma_f32_16x16x32_bf16(af[i], bfr[j], acc[i][j], 0, 0, 0);
    }
}

// ---------------- router GEMM1: z-split 3-term (fp32-accurate sum) ----------

__global__ __launch_bounds__(256) void router_gemm1_3(
    const bf16* __restrict__ xh, const bf16* __restrict__ xl,
    const bf16* __restrict__ wTh, const bf16* __restrict__ wTl,
    float* __restrict__ hp0, float* __restrict__ hp1, float* __restrict__ hp2) {
    __shared__ SMemStd sm;
    const int z = blockIdx.z;
    const bf16* Ab = (z == 2) ? xl : xh;
    const bf16* Bb = (z == 1) ? wTl : wTh;
    float* hp = (z == 0) ? hp0 : (z == 1 ? hp1 : hp2);
    const int tid = threadIdx.x;
    const int mbase = blockIdx.x * 128, nbase = blockIdx.y * 128;
    int c0 = tid, c1 = tid + 256;
    const bf16* gA0 = Ab + (size_t)(mbase + (c0 >> 2)) * D_MODEL + swz_src_q(c0) * 8;
    const bf16* gA1 = Ab + (size_t)(mbase + (c1 >> 2)) * D_MODEL + swz_src_q(c1) * 8;
    const bf16* Bt = Bb + (size_t)nbase * D_MODEL;
    const bf16* gB0 = Bt + (size_t)(c0 >> 2) * D_MODEL + swz_src_q(c0) * 8;
    const bf16* gB1 = Bt + (size_t)(c1 >> 2) * D_MODEL + swz_src_q(c1) * 8;
    f32x4 acc[4][4] = {};
    gemm_core_async(gA0, gA1, gB0, gB1, D_MODEL, sm.As, sm.Bs, acc);
    const int lane = tid & 63;
    const int w = tid >> 6;
    const int wm = w & 1, wn = w >> 1;
    const int lc = lane & 15, quad = lane >> 4;
    #pragma unroll
    for (int i = 0; i < 4; ++i)
        #pragma unroll
        for (int j = 0; j < 4; ++j) {
            int col = nbase + wn * 64 + j * 16 + lc;
            #pragma unroll
            for (int r = 0; r < 4; ++r) {
                int row = mbase + wm * 64 + i * 16 + quad * 4 + r;
                hp[(size_t)row * H_R + col] = acc[i][j][r];
            }
        }
}

// ---------------- fused LayerNorm + GELU + logits + top-2 -------------------
// NO count atomics (route_pack derives counts). meta[24] = tie-flag counter.

__global__ __launch_bounds__(256) void ln_router2(
    const float* __restrict__ hp0, const float* __restrict__ hp1,
    const float* __restrict__ hp2, const float* __restrict__ r1b,
    const float* __restrict__ g, const float* __restrict__ bta,
    const float* __restrict__ r2w, const float* __restrict__ r2b,
    const float* __restrict__ temp, const float* __restrict__ rbias,
    int* __restrict__ top_i, float* __restrict__ top_p,
    int* __restrict__ flaglist, int* __restrict__ meta) {
    __shared__ float Wl[H_R * N_EXP];
    int tid = threadIdx.x;
    for (int i = tid; i < H_R * N_EXP; i += 256) Wl[i] = r2w[i];
    __syncthreads();
    int w = tid >> 6, lane = tid & 63;
    int t = blockIdx.x * 4 + w;
    size_t rbase = (size_t)t * H_R;
    int k0 = lane * 8;
    float v[8];
    {
        f32x4 a0 = *(const f32x4*)(hp0 + rbase + k0);
        f32x4 a1 = *(const f32x4*)(hp0 + rbase + k0 + 4);
        f32x4 b0 = *(const f32x4*)(hp1 + rbase + k0);
        f32x4 b1 = *(const f32x4*)(hp1 + rbase + k0 + 4);
        f32x4 c0 = *(const f32x4*)(hp2 + rbase + k0);
        f32x4 c1 = *(const f32x4*)(hp2 + rbase + k0 + 4);
        f32x4 d0 = *(const f32x4*)(r1b + k0);
        f32x4 d1 = *(const f32x4*)(r1b + k0 + 4);
        #pragma unroll
        for (int k = 0; k < 4; ++k) {
            v[k]     = a0[k] + b0[k] + c0[k] + d0[k];
            v[k + 4] = a1[k] + b1[k] + c1[k] + d1[k];
        }
    }
    float s = 0.f;
    #pragma unroll
    for (int k = 0; k < 8; ++k) s += v[k];
    #pragma unroll
    for (int off = 32; off; off >>= 1) s += __shfl_xor(s, off);
    float mu = s * (1.0f / H_R);
    float q = 0.f;
    #pragma unroll
    for (int k = 0; k < 8; ++k) { float d = v[k] - mu; q += d * d; }
    #pragma unroll
    for (int off = 32; off; off >>= 1) q += __shfl_xor(q, off);
    float scl = 1.0f / sqrtf(q * (1.0f / H_R) + 1e-5f);
    f32x4 g0 = *(const f32x4*)(g + k0), g1 = *(const f32x4*)(g + k0 + 4);
    f32x4 b0 = *(const f32x4*)(bta + k0), b1v = *(const f32x4*)(bta + k0 + 4);
    float G[8] = {g0[0], g0[1], g0[2], g0[3], g1[0], g1[1], g1[2], g1[3]};
    float B[8] = {b0[0], b0[1], b0[2], b0[3], b1v[0], b1v[1], b1v[2], b1v[3]};
    float acc[N_EXP] = {};
    #pragma unroll
    for (int k = 0; k < 8; ++k) {
        float y = gelu_f((v[k] - mu) * scl * G[k] + B[k]);
        const float* wr = &Wl[(k0 + k) * N_EXP];
        #pragma unroll
        for (int e = 0; e < N_EXP; ++e) acc[e] += y * wr[e];
    }
    #pragma unroll
    for (int e = 0; e < N_EXP; ++e)
        #pragma unroll
        for (int off = 32; off; off >>= 1) acc[e] += __shfl_xor(acc[e], off);
    if (lane == 0) {
        float tinv = 1.0f / temp[0];
        float lg[N_EXP];
        #pragma unroll
        for (int e = 0; e < N_EXP; ++e) lg[e] = (acc[e] + r2b[e]) * tinv + rbias[e];
        float v1 = -1e30f; int i1 = 0;
        #pragma unroll
        for (int e = 0; e < N_EXP; ++e) if (lg[e] > v1) { v1 = lg[e]; i1 = e; }
        float v2 = -1e30f; int i2 = 0;
        #pragma unroll
        for (int e = 0; e < N_EXP; ++e) if (e != i1 && lg[e] > v2) { v2 = lg[e]; i2 = e; }
        float v3 = -1e30f;
        #pragma unroll
        for (int e = 0; e < N_EXP; ++e) if (e != i1 && e != i2 && lg[e] > v3) v3 = lg[e];
        float ssum = 0.f;
        #pragma unroll
        for (int e = 0; e < N_EXP; ++e) ssum += __expf(lg[e] - v1);
        float inv = 1.0f / ssum;
        top_i[2 * t] = i1; top_i[2 * t + 1] = i2;
        top_p[2 * t] = inv;
        top_p[2 * t + 1] = __expf(v2 - v1) * inv;
        if (v2 - v3 < 1e-3f) {
            int ix = atomicAdd(&meta[24], 1);
            if (ix < FLAG_CAP) flaglist[ix] = t;
        }
    }
}

// ---------------- fp64 exact rescue for near-tie tokens ---------------------

__global__ __launch_bounds__(256) void router_rescue(
    const float* __restrict__ x, const float* __restrict__ r1w,
    const float* __restrict__ r1b, const float* __restrict__ lng,
    const float* __restrict__ lnb, const float* __restrict__ r2w,
    const float* __restrict__ r2b, const float* __restrict__ temp,
    const float* __restrict__ rbias, const int* __restrict__ flaglist,
    const int* __restrict__ meta, int* __restrict__ top_i, float* __restrict__ top_p) {
    int n = meta[24]; if (n > FLAG_CAP) n = FLAG_CAP;
    if ((int)blockIdx.x >= n) return;
    int t = flaglist[blockIdx.x];
    __shared__ double xs[D_MODEL];
    __shared__ double hbuf[H_R];
    __shared__ double red[8];
    int tid = threadIdx.x;
    for (int k = tid; k < D_MODEL; k += 256) xs[k] = (double)x[(size_t)t * D_MODEL + k];
    __syncthreads();
    for (int c = tid; c < H_R; c += 256) {
        double s = 0.0;
        for (int k = 0; k < D_MODEL; ++k) s += xs[k] * (double)r1w[(size_t)k * H_R + c];
        hbuf[c] = s + (double)r1b[c];
    }
    __syncthreads();
    double ls = 0.0;
    for (int c = tid; c < H_R; c += 256) ls += hbuf[c];
    #pragma unroll
    for (int off = 32; off; off >>= 1) ls += __shfl_xor(ls, off);
    if ((tid & 63) == 0) red[tid >> 6] = ls;
    __syncthreads();
    double mu = (red[0] + red[1] + red[2] + red[3]) * (1.0 / H_R);
    __syncthreads();
    double q = 0.0;
    for (int c = tid; c < H_R; c += 256) { double d = hbuf[c] - mu; q += d * d; }
    #pragma unroll
    for (int off = 32; off; off >>= 1) q += __shfl_xor(q, off);
    if ((tid & 63) == 0) red[tid >> 6] = q;
    __syncthreads();
    double var = (red[0] + red[1] + red[2] + red[3]) * (1.0 / H_R);
    double scl = 1.0 / sqrt(var + 1e-5);
    __syncthreads();
    for (int c = tid; c < H_R; c += 256) {
        double y = (hbuf[c] - mu) * scl * (double)lng[c] + (double)lnb[c];
        hbuf[c] = 0.5 * y * (1.0 + erf(y * 0.70710678118654752440));
    }
    __syncthreads();
    if (tid < N_EXP) {
        double s = 0.0;
        for (int k = 0; k < H_R; ++k) s += hbuf[k] * (double)r2w[k * N_EXP + tid];
        red[tid] = (s + (double)r2b[tid]) / (double)temp[0] + (double)rbias[tid];
    }
    __syncthreads();
    if (tid == 0) {
        double lg[N_EXP];
        #pragma unroll
        for (int e = 0; e < N_EXP; ++e) lg[e] = red[e];
        double v1 = -1e300; int i1 = 0;
        for (int e = 0; e < N_EXP; ++e) if (lg[e] > v1) { v1 = lg[e]; i1 = e; }
        double v2 = -1e300; int i2 = 0;
        for (int e = 0; e < N_EXP; ++e) if (e != i1 && lg[e] > v2) { v2 = lg[e]; i2 = e; }
        double s = 0.0;
        for (int e = 0; e < N_EXP; ++e) s += exp(lg[e] - v1);
        double inv = 1.0 / s;
        top_i[2 * t] = i1; top_i[2 * t + 1] = i2;
        top_p[2 * t] = (float)inv;
        top_p[2 * t + 1] = (float)(exp(v2 - v1) * inv);
    }
}

// ---------------- route_pack: count + scan + scatter, zero global atomics ---
// ONE block, 1024 threads, 8 tokens (16 assignments) per thread.
// LDS 6x1024 Hillis-Steele inclusive scan -> deterministic positions.

#define RP_T 1024
#define RP_TOK (N_TOK / RP_T)   // 8 tokens per thread

__global__ __launch_bounds__(1024) void route_pack(
    const int* __restrict__ top_i, int* __restrict__ meta,
    int* __restrict__ atok, int* __restrict__ ainv) {
    __shared__ int S[N_EXP][RP_T];
    __shared__ int segbase[N_EXP + 1];
    int tid = threadIdx.x;
    int e_loc[2 * RP_TOK];
    int cnt[N_EXP];
    #pragma unroll
    for (int e = 0; e < N_EXP; ++e) cnt[e] = 0;
    int t0 = tid * RP_TOK;
    #pragma unroll
    for (int q = 0; q < (2 * RP_TOK) / 4; ++q) {
        i32x4 v = *(const i32x4*)(top_i + 2 * t0 + q * 4);
        #pragma unroll
        for (int k = 0; k < 4; ++k) {
            int e = v[k];
            e_loc[q * 4 + k] = e;
            #pragma unroll
            for (int ee = 0; ee < N_EXP; ++ee) if (e == ee) cnt[ee]++;
        }
    }
    #pragma unroll
    for (int e = 0; e < N_EXP; ++e) S[e][tid] = cnt[e];
    __syncthreads();
    // inclusive scan over tid for each expert
    for (int off = 1; off < RP_T; off <<= 1) {
        int tmp[N_EXP];
        #pragma unroll
        for (int e = 0; e < N_EXP; ++e)
            tmp[e] = (tid >= off) ? S[e][tid - off] : 0;
        __syncthreads();
        #pragma unroll
        for (int e = 0; e < N_EXP; ++e) S[e][tid] += tmp[e];
        __syncthreads();
    }
    if (tid == 0) {
        int o = 0;
        #pragma unroll
        for (int e = 0; e < N_EXP; ++e) {
            segbase[e] = o;
            int tot = S[e][RP_T - 1];
            meta[e] = tot;       // counts
            meta[8 + e] = o;     // offsets
            o += tot;
        }
        segbase[N_EXP] = o;
    }
    __syncthreads();
    int pos[N_EXP];
    #pragma unroll
    for (int e = 0; e < N_EXP; ++e)
        pos[e] = segbase[e] + S[e][tid] - cnt[e];   // exclusive prefix + segment base
    #pragma unroll
    for (int k = 0; k < 2 * RP_TOK; ++k) {
        int e = e_loc[k];
        int a = 0;
        #pragma unroll
        for (int ee = 0; ee < N_EXP; ++ee) if (e == ee) a = pos[ee]++;
        atok[a] = t0 + (k >> 1);
        ainv[2 * t0 + k] = a;
    }
}

// ---------------- expert GEMMs (grid: m fastest, then n, then e) ------------

__global__ __launch_bounds__(256) void expert_gemm1(
    const bf16* __restrict__ xb, const bf16* __restrict__ W1T,
    const float* __restrict__ b1, const int* __restrict__ meta,
    const int* __restrict__ atok, bf16* __restrict__ act) {
    int e = blockIdx.z;
    int rows = meta[e];
    int mloc = blockIdx.x * 128;
    if (mloc >= rows) return;
    int base = meta[8 + e];
    __shared__ SMemStd sm;
    int tid = threadIdx.x;
    int nbase = blockIdx.y * 128;
    int c0 = tid, c1 = tid + 256;
    int r0 = mloc + (c0 >> 2); if (r0 > rows - 1) r0 = rows - 1;
    int r1 = mloc + (c1 >> 2); if (r1 > rows - 1) r1 = rows - 1;
    const bf16* gA0 = xb + (size_t)atok[base + r0] * D_MODEL + swz_src_q(c0) * 8;
    const bf16* gA1 = xb + (size_t)atok[base + r1] * D_MODEL + swz_src_q(c1) * 8;
    const bf16* Bt = W1T + ((size_t)e * F_FF + nbase) * D_MODEL;
    const bf16* gB0 = Bt + (size_t)(c0 >> 2) * D_MODEL + swz_src_q(c0) * 8;
    const bf16* gB1 = Bt + (size_t)(c1 >> 2) * D_MODEL + swz_src_q(c1) * 8;
    f32x4 acc[4][4] = {};
    gemm_core_async(gA0, gA1, gB0, gB1, D_MODEL, sm.As, sm.Bs, acc);
    const int lane = tid & 63;
    const int w = tid >> 6;
    const int wm = w & 1, wn = w >> 1;
    const int lc = lane & 15, quad = lane >> 4;
    bool odd = (e & 1) != 0;
    #pragma unroll
    for (int i = 0; i < 4; ++i)
        #pragma unroll
        for (int j = 0; j < 4; ++j) {
            int col = nbase + wn * 64 + j * 16 + lc;
            float bias = b1[e * F_FF + col];
            #pragma unroll
            for (int r = 0; r < 4; ++r) {
                int rloc = mloc + wm * 64 + i * 16 + quad * 4 + r;
                if (rloc < rows) {
                    float vv = acc[i][j][r] + bias;
                    vv = odd ? silu_f(vv) : gelu_f(vv);
                    act[(size_t)(base + rloc) * F_FF + col] = (bf16)vv;
                }
            }
        }
}

__global__ __launch_bounds__(256) void expert_gemm2(
    const bf16* __restrict__ act, const bf16* __restrict__ W2T,
    const float* __restrict__ b2, const int* __restrict__ meta,
    float* __restrict__ eo) {
    int e = blockIdx.z;
    int rows = meta[e];
    int mloc = blockIdx.x * 128;
    if (mloc >= rows) return;
    int base = meta[8 + e];
    __shared__ SMemStd sm;
    int tid = threadIdx.x;
    int nbase = blockIdx.y * 128;
    int c0 = tid, c1 = tid + 256;
    int r0 = mloc + (c0 >> 2); if (r0 > rows - 1) r0 = rows - 1;
    int r1 = mloc + (c1 >> 2); if (r1 > rows - 1) r1 = rows - 1;
    const bf16* gA0 = act + (size_t)(base + r0) * F_FF + swz_src_q(c0) * 8;
    const bf16* gA1 = act + (size_t)(base + r1) * F_FF + swz_src_q(c1) * 8;
    const bf16* Bt = W2T + ((size_t)e * D_MODEL + nbase) * F_FF;
    const bf16* gB0 = Bt + (size_t)(c0 >> 2) * F_FF + swz_src_q(c0) * 8;
    const bf16* gB1 = Bt + (size_t)(c1 >> 2) * F_FF + swz_src_q(c1) * 8;
    f32x4 acc[4][4] = {};
    gemm_core_async(gA0, gA1, gB0, gB1, F_FF, sm.As, sm.Bs, acc);
    const int lane = tid & 63;
    const int w = tid >> 6;
    const int wm = w & 1, wn = w >> 1;
    const int lc = lane & 15, quad = lane >> 4;
    #pragma unroll
    for (int i = 0; i < 4; ++i)
        #pragma unroll
        for (int j = 0; j < 4; ++j) {
            int col = nbase + wn * 64 + j * 16 + lc;
            float bias = b2[e * D_MODEL + col];
            #pragma unroll
            for (int r = 0; r < 4; ++r) {
                int rloc = mloc + wm * 64 + i * 16 + quad * 4 + r;
                if (rloc < rows)
                    eo[(size_t)(base + rloc) * D_MODEL + col] = acc[i][j][r] + bias;
            }
        }
}

// ---------------- weighted combine ------------------------------------------

__global__ __launch_bounds__(256) void combine_kernel(
    const float* __restrict__ eo, const int* __restrict__ ainv,
    const float* __restrict__ top_p, float* __restrict__ out) {
    int t = blockIdx.x;
    int s0 = ainv[2 * t], s1 = ainv[2 * t + 1];
    float p0 = top_p[2 * t], p1 = top_p[2 * t + 1];
    int c = threadIdx.x * 4;
    f32x4 a = *(const f32x4*)(eo + (size_t)s0 * D_MODEL + c);
    f32x4 b = *(const f32x4*)(eo + (size_t)s1 * D_MODEL + c);
    f32x4 o;
    #pragma unroll
    for (int k = 0; k < 4; ++k) o[k] = a[k] * p0 + b[k] * p1;
    *(f32x4*)(out + (size_t)t * D_MODEL + c) = o;
}

// ---------------- launch ----------------------------------------------------

extern "C" void kernel_launch(void* const* d_in, const int* in_sizes, int n_in,
                              void* d_out, int out_size, void* d_ws, size_t ws_size,
                              hipStream_t stream) {
    const float* x     = (const float*)d_in[0];
    const float* r1w   = (const float*)d_in[1];
    const float* r1b   = (const float*)d_in[2];
    const float* lng   = (const float*)d_in[3];
    const float* lnb   = (const float*)d_in[4];
    const float* r2w   = (const float*)d_in[5];
    const float* r2b   = (const float*)d_in[6];
    const float* temp  = (const float*)d_in[7];
    const float* rbias = (const float*)d_in[8];
    const float* W1    = (const float*)d_in[9];
    const float* b1    = (const float*)d_in[10];
    const float* W2    = (const float*)d_in[11];
    const float* b2    = (const float*)d_in[12];
    float* out = (float*)d_out;

    char* ws = (char*)d_ws;
    size_t off = 0;
    auto alloc = [&](size_t bytes) -> void* {
        void* p = ws + off;
        off = (off + bytes + 255) & ~(size_t)255;
        return p;
    };
    bf16*  xh    = (bf16*)alloc((size_t)N_TOK * D_MODEL * 2);
    bf16*  xl    = (bf16*)alloc((size_t)N_TOK * D_MODEL * 2);
    bf16*  r1wTh = (bf16*)alloc((size_t)H_R * D_MODEL * 2);
    bf16*  r1wTl = (bf16*)alloc((size_t)H_R * D_MODEL * 2);
    bf16*  W1T   = (bf16*)alloc((size_t)N_EXP * F_FF * D_MODEL * 2);
    bf16*  W2T   = (bf16*)alloc((size_t)N_EXP * D_MODEL * F_FF * 2);
    float* hp0   = (float*)alloc((size_t)N_TOK * H_R * 4);
    int*   top_i = (int*)alloc((size_t)N_TOK * 2 * 4);
    float* top_p = (float*)alloc((size_t)N_TOK * 2 * 4);
    int*   meta  = (int*)alloc(256);
    int*   flags = (int*)alloc(FLAG_CAP * 4);
    int*   atok  = (int*)alloc((size_t)2 * N_TOK * 4);
    int*   ainv  = (int*)alloc((size_t)2 * N_TOK * 4);
    bf16*  actb  = (bf16*)alloc((size_t)2 * N_TOK * F_FF * 2);
    float* eo    = (float*)alloc((size_t)2 * N_TOK * D_MODEL * 4);
    float* hp1 = (float*)actb;
    float* hp2 = (float*)((char*)actb + (size_t)N_TOK * H_R * 4);
    (void)ws_size; (void)n_in; (void)in_sizes;

    hipMemsetAsync(meta, 0, 256, stream);

    convert_x_split<<<(N_TOK * D_MODEL) / (256 * 8), 256, 0, stream>>>(x, xh, xl);
    transpose_split<<<dim3(H_R / 32, D_MODEL / 32, 1), 256, 0, stream>>>(
        r1w, r1wTh, r1wTl, D_MODEL, H_R);
    transpose_bf16_64<<<dim3(F_FF / 64, D_MODEL / 64, N_EXP), 256, 0, stream>>>(
        W1, W1T, D_MODEL, F_FF);
    transpose_bf16_64<<<dim3(D_MODEL / 64, F_FF / 64, N_EXP), 256, 0, stream>>>(
        W2, W2T, F_FF, D_MODEL);

    router_gemm1_3<<<dim3(N_TOK / 128, H_R / 128, 3), 256, 0, stream>>>(
        xh, xl, r1wTh, r1wTl, hp0, hp1, hp2);
    ln_router2<<<N_TOK / 4, 256, 0, stream>>>(
        hp0, hp1, hp2, r1b, lng, lnb, r2w, r2b, temp, rbias, top_i, top_p, flags, meta);
    router_rescue<<<FLAG_CAP, 256, 0, stream>>>(
        x, r1w, r1b, lng, lnb, r2w, r2b, temp, rbias, flags, meta, top_i, top_p);
    route_pack<<<1, RP_T, 0, stream>>>(top_i, meta, atok, ainv);

    expert_gemm1<<<dim3(N_TOK / 128, F_FF / 128, N_EXP), 256, 0, stream>>>(
        xh, W1T, b1, meta, atok, actb);
    expert_gemm2<<<dim3(N_TOK / 128, D_MODEL / 128, N_EXP), 256, 0, stream>>>(
        actb, W2T, b2, meta, eo);
    combine_kernel<<<N_TOK, 256, 0, stream>>>(eo, ainv, top_p, out);
}

// Round 7
// 556.244 us; speedup vs baseline: 1.5874x; 1.0782x over previous
//
#include <hip/hip_runtime.h>
#include <hip/hip_bf16.h>
#include <stdint.h>

typedef __bf16 bf16;
typedef bf16 bf16x8 __attribute__((ext_vector_type(8)));
typedef bf16 bf16x4 __attribute__((ext_vector_type(4)));
typedef float f32x4 __attribute__((ext_vector_type(4)));
typedef int i32x4 __attribute__((ext_vector_type(4)));

#define N_TOK 8192
#define D_MODEL 1024
#define H_R 512
#define N_EXP 6
#define F_FF 1536
#define FLAG_CAP 1024

// Abramowitz-Stegun 7.1.26: |err| <= 1.5e-7
__device__ __forceinline__ float erf_fast(float x) {
    float ax = fabsf(x);
    float t = 1.0f / (1.0f + 0.3275911f * ax);
    float p = t * (0.254829592f + t * (-0.284496736f + t * (1.421413741f +
              t * (-1.453152027f + t * 1.061405429f))));
    float r = 1.0f - p * __expf(-ax * ax);
    return copysignf(r, x);
}
__device__ __forceinline__ float gelu_f(float x) {
    return 0.5f * x * (1.0f + erf_fast(x * 0.70710678118654752f));
}
__device__ __forceinline__ float silu_f(float x) {
    return x * (1.0f / (1.0f + __expf(-x)));
}

typedef __attribute__((address_space(1))) const void* gas1;
typedef __attribute__((address_space(3))) void* las3;

__device__ __forceinline__ void gload16(const void* g, void* l) {
    __builtin_amdgcn_global_load_lds((gas1)g, (las3)l, 16, 0, 0);
}

// LDS chunk swizzle: row r's logical 16B chunk q lives at chunk-slot (q + (r>>1)) & 3.
__device__ __forceinline__ int swz_src_q(int c) {
    return (((c & 3) - ((c >> 2) >> 1)) & 3);
}

// ---------------- conversion / transpose ------------------------------------

__global__ __launch_bounds__(256) void convert_x_split(
    const float* __restrict__ x, bf16* __restrict__ xh, bf16* __restrict__ xl) {
    size_t i = ((size_t)blockIdx.x * 256 + threadIdx.x) * 8;
    f32x4 a = *(const f32x4*)(x + i);
    f32x4 b = *(const f32x4*)(x + i + 4);
    float v[8] = {a[0], a[1], a[2], a[3], b[0], b[1], b[2], b[3]};
    bf16x8 vh, vl;
    #pragma unroll
    for (int k = 0; k < 8; ++k) {
        bf16 h = (bf16)v[k];
        vh[k] = h;
        vl[k] = (bf16)(v[k] - (float)h);
    }
    *(bf16x8*)(xh + i) = vh;
    *(bf16x8*)(xl + i) = vl;
}

__global__ __launch_bounds__(256) void transpose_bf16_64(
    const float* __restrict__ in, bf16* __restrict__ out, int R, int C) {
    __shared__ float tile[64][65];
    const float* inp = in + (size_t)blockIdx.z * R * C;
    bf16* op = out + (size_t)blockIdx.z * R * C;
    int tx = threadIdx.x & 15, ty = threadIdx.x >> 4;
    int r0 = blockIdx.y * 64, c0 = blockIdx.x * 64;
    #pragma unroll
    for (int p = 0; p < 4; ++p) {
        int row = p * 16 + ty;
        f32x4 v = *(const f32x4*)(inp + (size_t)(r0 + row) * C + c0 + tx * 4);
        tile[row][tx * 4 + 0] = v[0];
        tile[row][tx * 4 + 1] = v[1];
        tile[row][tx * 4 + 2] = v[2];
        tile[row][tx * 4 + 3] = v[3];
    }
    __syncthreads();
    #pragma unroll
    for (int p = 0; p < 4; ++p) {
        int cc = p * 16 + ty;
        bf16x4 o;
        #pragma unroll
        for (int k = 0; k < 4; ++k) o[k] = (bf16)tile[tx * 4 + k][cc];
        *(bf16x4*)(op + (size_t)(c0 + cc) * R + r0 + tx * 4) = o;
    }
}

__global__ __launch_bounds__(256) void transpose_split(
    const float* __restrict__ in, bf16* __restrict__ oh, bf16* __restrict__ ol,
    int R, int C) {
    __shared__ float tile[32][33];
    int tx = threadIdx.x & 31, ty = threadIdx.x >> 5;
    int r0 = blockIdx.y * 32, c0 = blockIdx.x * 32;
    #pragma unroll
    for (int yy = ty; yy < 32; yy += 8)
        tile[yy][tx] = in[(size_t)(r0 + yy) * C + c0 + tx];
    __syncthreads();
    #pragma unroll
    for (int yy = ty; yy < 32; yy += 8) {
        float v = tile[tx][yy];
        bf16 h = (bf16)v;
        size_t o = (size_t)(c0 + yy) * R + r0 + tx;
        oh[o] = h;
        ol[o] = (bf16)(v - (float)h);
    }
}

// ---------------- 128x128 bf16 MFMA GEMM core (async staging, swizzled LDS) --

struct SMemStd {
    alignas(16) bf16 As[128 * 32];
    alignas(16) bf16 Bs[128 * 32];
};

__device__ __forceinline__ void gemm_core_async(
    const bf16* gA0, const bf16* gA1, const bf16* gB0, const bf16* gB1,
    int K, bf16* As, bf16* Bs, f32x4 acc[4][4]) {
    const int tid = threadIdx.x;
    const int lane = tid & 63;
    const int w = tid >> 6;
    const int wm = w & 1, wn = w >> 1;
    const int lc = lane & 15;
    const int koff = ((((lane >> 4) + (lc >> 1)) & 3) * 8);
    bf16* lA0 = As + w * 512;
    bf16* lA1 = As + 2048 + w * 512;
    bf16* lB0 = Bs + w * 512;
    bf16* lB1 = Bs + 2048 + w * 512;
    for (int kb = 0; kb < K; kb += 32) {
        __syncthreads();
        gload16(gA0 + kb, lA0);
        gload16(gA1 + kb, lA1);
        gload16(gB0 + kb, lB0);
        gload16(gB1 + kb, lB1);
        __syncthreads();
        bf16x8 af[4], bfr[4];
        #pragma unroll
        for (int i = 0; i < 4; ++i)
            af[i] = *(const bf16x8*)(As + (wm * 64 + i * 16 + lc) * 32 + koff);
        #pragma unroll
        for (int j = 0; j < 4; ++j)
            bfr[j] = *(const bf16x8*)(Bs + (wn * 64 + j * 16 + lc) * 32 + koff);
        #pragma unroll
        for (int i = 0; i < 4; ++i)
            #pragma unroll
            for (int j = 0; j < 4; ++j)
                acc[i][j] = __builtin_amdgcn_mfma_f32_16x16x32_bf16(af[i], bfr[j], acc[i][j], 0, 0, 0);
    }
}

// ---------------- router GEMM1: z-split 3-term (fp32-accurate sum) ----------
// grid (x=nbase(4), y=mtile(64), z=3): n-fastest -> A-tile reuse stays in L2

__global__ __launch_bounds__(256) void router_gemm1_3(
    const bf16* __restrict__ xh, const bf16* __restrict__ xl,
    const bf16* __restrict__ wTh, const bf16* __restrict__ wTl,
    float* __restrict__ hp0, float* __restrict__ hp1, float* __restrict__ hp2) {
    __shared__ SMemStd sm;
    const int z = blockIdx.z;
    const bf16* Ab = (z == 2) ? xl : xh;
    const bf16* Bb = (z == 1) ? wTl : wTh;
    float* hp = (z == 0) ? hp0 : (z == 1 ? hp1 : hp2);
    const int tid = threadIdx.x;
    const int mbase = blockIdx.y * 128, nbase = blockIdx.x * 128;
    int c0 = tid, c1 = tid + 256;
    const bf16* gA0 = Ab + (size_t)(mbase + (c0 >> 2)) * D_MODEL + swz_src_q(c0) * 8;
    const bf16* gA1 = Ab + (size_t)(mbase + (c1 >> 2)) * D_MODEL + swz_src_q(c1) * 8;
    const bf16* Bt = Bb + (size_t)nbase * D_MODEL;
    const bf16* gB0 = Bt + (size_t)(c0 >> 2) * D_MODEL + swz_src_q(c0) * 8;
    const bf16* gB1 = Bt + (size_t)(c1 >> 2) * D_MODEL + swz_src_q(c1) * 8;
    f32x4 acc[4][4] = {};
    gemm_core_async(gA0, gA1, gB0, gB1, D_MODEL, sm.As, sm.Bs, acc);
    const int lane = tid & 63;
    const int w = tid >> 6;
    const int wm = w & 1, wn = w >> 1;
    const int lc = lane & 15, quad = lane >> 4;
    #pragma unroll
    for (int i = 0; i < 4; ++i)
        #pragma unroll
        for (int j = 0; j < 4; ++j) {
            int col = nbase + wn * 64 + j * 16 + lc;
            #pragma unroll
            for (int r = 0; r < 4; ++r) {
                int row = mbase + wm * 64 + i * 16 + quad * 4 + r;
                hp[(size_t)row * H_R + col] = acc[i][j][r];
            }
        }
}

// ---------------- fused LayerNorm + GELU + logits + top-2 -------------------
// NO count atomics (route_pack derives counts). meta[24] = tie-flag counter.

__global__ __launch_bounds__(256) void ln_router2(
    const float* __restrict__ hp0, const float* __restrict__ hp1,
    const float* __restrict__ hp2, const float* __restrict__ r1b,
    const float* __restrict__ g, const float* __restrict__ bta,
    const float* __restrict__ r2w, const float* __restrict__ r2b,
    const float* __restrict__ temp, const float* __restrict__ rbias,
    int* __restrict__ top_i, float* __restrict__ top_p,
    int* __restrict__ flaglist, int* __restrict__ meta) {
    __shared__ float Wl[H_R * N_EXP];
    int tid = threadIdx.x;
    for (int i = tid; i < H_R * N_EXP; i += 256) Wl[i] = r2w[i];
    __syncthreads();
    int w = tid >> 6, lane = tid & 63;
    int t = blockIdx.x * 4 + w;
    size_t rbase = (size_t)t * H_R;
    int k0 = lane * 8;
    float v[8];
    {
        f32x4 a0 = *(const f32x4*)(hp0 + rbase + k0);
        f32x4 a1 = *(const f32x4*)(hp0 + rbase + k0 + 4);
        f32x4 b0 = *(const f32x4*)(hp1 + rbase + k0);
        f32x4 b1 = *(const f32x4*)(hp1 + rbase + k0 + 4);
        f32x4 c0 = *(const f32x4*)(hp2 + rbase + k0);
        f32x4 c1 = *(const f32x4*)(hp2 + rbase + k0 + 4);
        f32x4 d0 = *(const f32x4*)(r1b + k0);
        f32x4 d1 = *(const f32x4*)(r1b + k0 + 4);
        #pragma unroll
        for (int k = 0; k < 4; ++k) {
            v[k]     = a0[k] + b0[k] + c0[k] + d0[k];
            v[k + 4] = a1[k] + b1[k] + c1[k] + d1[k];
        }
    }
    float s = 0.f;
    #pragma unroll
    for (int k = 0; k < 8; ++k) s += v[k];
    #pragma unroll
    for (int off = 32; off; off >>= 1) s += __shfl_xor(s, off);
    float mu = s * (1.0f / H_R);
    float q = 0.f;
    #pragma unroll
    for (int k = 0; k < 8; ++k) { float d = v[k] - mu; q += d * d; }
    #pragma unroll
    for (int off = 32; off; off >>= 1) q += __shfl_xor(q, off);
    float scl = 1.0f / sqrtf(q * (1.0f / H_R) + 1e-5f);
    f32x4 g0 = *(const f32x4*)(g + k0), g1 = *(const f32x4*)(g + k0 + 4);
    f32x4 b0 = *(const f32x4*)(bta + k0), b1v = *(const f32x4*)(bta + k0 + 4);
    float G[8] = {g0[0], g0[1], g0[2], g0[3], g1[0], g1[1], g1[2], g1[3]};
    float B[8] = {b0[0], b0[1], b0[2], b0[3], b1v[0], b1v[1], b1v[2], b1v[3]};
    float acc[N_EXP] = {};
    #pragma unroll
    for (int k = 0; k < 8; ++k) {
        float y = gelu_f((v[k] - mu) * scl * G[k] + B[k]);
        const float* wr = &Wl[(k0 + k) * N_EXP];
        #pragma unroll
        for (int e = 0; e < N_EXP; ++e) acc[e] += y * wr[e];
    }
    #pragma unroll
    for (int e = 0; e < N_EXP; ++e)
        #pragma unroll
        for (int off = 32; off; off >>= 1) acc[e] += __shfl_xor(acc[e], off);
    if (lane == 0) {
        float tinv = 1.0f / temp[0];
        float lg[N_EXP];
        #pragma unroll
        for (int e = 0; e < N_EXP; ++e) lg[e] = (acc[e] + r2b[e]) * tinv + rbias[e];
        float v1 = -1e30f; int i1 = 0;
        #pragma unroll
        for (int e = 0; e < N_EXP; ++e) if (lg[e] > v1) { v1 = lg[e]; i1 = e; }
        float v2 = -1e30f; int i2 = 0;
        #pragma unroll
        for (int e = 0; e < N_EXP; ++e) if (e != i1 && lg[e] > v2) { v2 = lg[e]; i2 = e; }
        float v3 = -1e30f;
        #pragma unroll
        for (int e = 0; e < N_EXP; ++e) if (e != i1 && e != i2 && lg[e] > v3) v3 = lg[e];
        float ssum = 0.f;
        #pragma unroll
        for (int e = 0; e < N_EXP; ++e) ssum += __expf(lg[e] - v1);
        float inv = 1.0f / ssum;
        top_i[2 * t] = i1; top_i[2 * t + 1] = i2;
        top_p[2 * t] = inv;
        top_p[2 * t + 1] = __expf(v2 - v1) * inv;
        if (v2 - v3 < 1e-3f) {
            int ix = atomicAdd(&meta[24], 1);
            if (ix < FLAG_CAP) flaglist[ix] = t;
        }
    }
}

// ---------------- fp64 exact rescue for near-tie tokens ---------------------

__global__ __launch_bounds__(256) void router_rescue(
    const float* __restrict__ x, const float* __restrict__ r1w,
    const float* __restrict__ r1b, const float* __restrict__ lng,
    const float* __restrict__ lnb, const float* __restrict__ r2w,
    const float* __restrict__ r2b, const float* __restrict__ temp,
    const float* __restrict__ rbias, const int* __restrict__ flaglist,
    const int* __restrict__ meta, int* __restrict__ top_i, float* __restrict__ top_p) {
    int n = meta[24]; if (n > FLAG_CAP) n = FLAG_CAP;
    if ((int)blockIdx.x >= n) return;
    int t = flaglist[blockIdx.x];
    __shared__ double xs[D_MODEL];
    __shared__ double hbuf[H_R];
    __shared__ double red[8];
    int tid = threadIdx.x;
    for (int k = tid; k < D_MODEL; k += 256) xs[k] = (double)x[(size_t)t * D_MODEL + k];
    __syncthreads();
    for (int c = tid; c < H_R; c += 256) {
        double s = 0.0;
        for (int k = 0; k < D_MODEL; ++k) s += xs[k] * (double)r1w[(size_t)k * H_R + c];
        hbuf[c] = s + (double)r1b[c];
    }
    __syncthreads();
    double ls = 0.0;
    for (int c = tid; c < H_R; c += 256) ls += hbuf[c];
    #pragma unroll
    for (int off = 32; off; off >>= 1) ls += __shfl_xor(ls, off);
    if ((tid & 63) == 0) red[tid >> 6] = ls;
    __syncthreads();
    double mu = (red[0] + red[1] + red[2] + red[3]) * (1.0 / H_R);
    __syncthreads();
    double q = 0.0;
    for (int c = tid; c < H_R; c += 256) { double d = hbuf[c] - mu; q += d * d; }
    #pragma unroll
    for (int off = 32; off; off >>= 1) q += __shfl_xor(q, off);
    if ((tid & 63) == 0) red[tid >> 6] = q;
    __syncthreads();
    double var = (red[0] + red[1] + red[2] + red[3]) * (1.0 / H_R);
    double scl = 1.0 / sqrt(var + 1e-5);
    __syncthreads();
    for (int c = tid; c < H_R; c += 256) {
        double y = (hbuf[c] - mu) * scl * (double)lng[c] + (double)lnb[c];
        hbuf[c] = 0.5 * y * (1.0 + erf(y * 0.70710678118654752440));
    }
    __syncthreads();
    if (tid < N_EXP) {
        double s = 0.0;
        for (int k = 0; k < H_R; ++k) s += hbuf[k] * (double)r2w[k * N_EXP + tid];
        red[tid] = (s + (double)r2b[tid]) / (double)temp[0] + (double)rbias[tid];
    }
    __syncthreads();
    if (tid == 0) {
        double lg[N_EXP];
        #pragma unroll
        for (int e = 0; e < N_EXP; ++e) lg[e] = red[e];
        double v1 = -1e300; int i1 = 0;
        for (int e = 0; e < N_EXP; ++e) if (lg[e] > v1) { v1 = lg[e]; i1 = e; }
        double v2 = -1e300; int i2 = 0;
        for (int e = 0; e < N_EXP; ++e) if (e != i1 && lg[e] > v2) { v2 = lg[e]; i2 = e; }
        double s = 0.0;
        for (int e = 0; e < N_EXP; ++e) s += exp(lg[e] - v1);
        double inv = 1.0 / s;
        top_i[2 * t] = i1; top_i[2 * t + 1] = i2;
        top_p[2 * t] = (float)inv;
        top_p[2 * t + 1] = (float)(exp(v2 - v1) * inv);
    }
}

// ---------------- route_pack: count + scan + scatter, zero global atomics ---

#define RP_T 1024
#define RP_TOK (N_TOK / RP_T)   // 8 tokens per thread

__global__ __launch_bounds__(1024) void route_pack(
    const int* __restrict__ top_i, int* __restrict__ meta,
    int* __restrict__ atok, int* __restrict__ ainv) {
    __shared__ int S[N_EXP][RP_T];
    __shared__ int segbase[N_EXP + 1];
    int tid = threadIdx.x;
    int e_loc[2 * RP_TOK];
    int cnt[N_EXP];
    #pragma unroll
    for (int e = 0; e < N_EXP; ++e) cnt[e] = 0;
    int t0 = tid * RP_TOK;
    #pragma unroll
    for (int q = 0; q < (2 * RP_TOK) / 4; ++q) {
        i32x4 v = *(const i32x4*)(top_i + 2 * t0 + q * 4);
        #pragma unroll
        for (int k = 0; k < 4; ++k) {
            int e = v[k];
            e_loc[q * 4 + k] = e;
            #pragma unroll
            for (int ee = 0; ee < N_EXP; ++ee) if (e == ee) cnt[ee]++;
        }
    }
    #pragma unroll
    for (int e = 0; e < N_EXP; ++e) S[e][tid] = cnt[e];
    __syncthreads();
    for (int off = 1; off < RP_T; off <<= 1) {
        int tmp[N_EXP];
        #pragma unroll
        for (int e = 0; e < N_EXP; ++e)
            tmp[e] = (tid >= off) ? S[e][tid - off] : 0;
        __syncthreads();
        #pragma unroll
        for (int e = 0; e < N_EXP; ++e) S[e][tid] += tmp[e];
        __syncthreads();
    }
    if (tid == 0) {
        int o = 0;
        #pragma unroll
        for (int e = 0; e < N_EXP; ++e) {
            segbase[e] = o;
            int tot = S[e][RP_T - 1];
            meta[e] = tot;
            meta[8 + e] = o;
            o += tot;
        }
        segbase[N_EXP] = o;
    }
    __syncthreads();
    int pos[N_EXP];
    #pragma unroll
    for (int e = 0; e < N_EXP; ++e)
        pos[e] = segbase[e] + S[e][tid] - cnt[e];
    #pragma unroll
    for (int k = 0; k < 2 * RP_TOK; ++k) {
        int e = e_loc[k];
        int a = 0;
        #pragma unroll
        for (int ee = 0; ee < N_EXP; ++ee) if (e == ee) a = pos[ee]++;
        atok[a] = t0 + (k >> 1);
        ainv[2 * t0 + k] = a;
    }
}

// ---------------- expert GEMMs (grid: x=nbase fastest, y=mtile, z=e) --------

__global__ __launch_bounds__(256) void expert_gemm1(
    const bf16* __restrict__ xb, const bf16* __restrict__ W1T,
    const float* __restrict__ b1, const int* __restrict__ meta,
    const int* __restrict__ atok, bf16* __restrict__ act) {
    int e = blockIdx.z;
    int rows = meta[e];
    int mloc = blockIdx.y * 128;
    if (mloc >= rows) return;
    int base = meta[8 + e];
    __shared__ SMemStd sm;
    int tid = threadIdx.x;
    int nbase = blockIdx.x * 128;
    int c0 = tid, c1 = tid + 256;
    int r0 = mloc + (c0 >> 2); if (r0 > rows - 1) r0 = rows - 1;
    int r1 = mloc + (c1 >> 2); if (r1 > rows - 1) r1 = rows - 1;
    const bf16* gA0 = xb + (size_t)atok[base + r0] * D_MODEL + swz_src_q(c0) * 8;
    const bf16* gA1 = xb + (size_t)atok[base + r1] * D_MODEL + swz_src_q(c1) * 8;
    const bf16* Bt = W1T + ((size_t)e * F_FF + nbase) * D_MODEL;
    const bf16* gB0 = Bt + (size_t)(c0 >> 2) * D_MODEL + swz_src_q(c0) * 8;
    const bf16* gB1 = Bt + (size_t)(c1 >> 2) * D_MODEL + swz_src_q(c1) * 8;
    f32x4 acc[4][4] = {};
    gemm_core_async(gA0, gA1, gB0, gB1, D_MODEL, sm.As, sm.Bs, acc);
    const int lane = tid & 63;
    const int w = tid >> 6;
    const int wm = w & 1, wn = w >> 1;
    const int lc = lane & 15, quad = lane >> 4;
    bool odd = (e & 1) != 0;
    #pragma unroll
    for (int i = 0; i < 4; ++i)
        #pragma unroll
        for (int j = 0; j < 4; ++j) {
            int col = nbase + wn * 64 + j * 16 + lc;
            float bias = b1[e * F_FF + col];
            #pragma unroll
            for (int r = 0; r < 4; ++r) {
                int rloc = mloc + wm * 64 + i * 16 + quad * 4 + r;
                if (rloc < rows) {
                    float vv = acc[i][j][r] + bias;
                    vv = odd ? silu_f(vv) : gelu_f(vv);
                    act[(size_t)(base + rloc) * F_FF + col] = (bf16)vv;
                }
            }
        }
}

__global__ __launch_bounds__(256) void expert_gemm2(
    const bf16* __restrict__ act, const bf16* __restrict__ W2T,
    const float* __restrict__ b2, const int* __restrict__ meta,
    float* __restrict__ eo) {
    int e = blockIdx.z;
    int rows = meta[e];
    int mloc = blockIdx.y * 128;
    if (mloc >= rows) return;
    int base = meta[8 + e];
    __shared__ SMemStd sm;
    int tid = threadIdx.x;
    int nbase = blockIdx.x * 128;
    int c0 = tid, c1 = tid + 256;
    int r0 = mloc + (c0 >> 2); if (r0 > rows - 1) r0 = rows - 1;
    int r1 = mloc + (c1 >> 2); if (r1 > rows - 1) r1 = rows - 1;
    const bf16* gA0 = act + (size_t)(base + r0) * F_FF + swz_src_q(c0) * 8;
    const bf16* gA1 = act + (size_t)(base + r1) * F_FF + swz_src_q(c1) * 8;
    const bf16* Bt = W2T + ((size_t)e * D_MODEL + nbase) * F_FF;
    const bf16* gB0 = Bt + (size_t)(c0 >> 2) * F_FF + swz_src_q(c0) * 8;
    const bf16* gB1 = Bt + (size_t)(c1 >> 2) * F_FF + swz_src_q(c1) * 8;
    f32x4 acc[4][4] = {};
    gemm_core_async(gA0, gA1, gB0, gB1, F_FF, sm.As, sm.Bs, acc);
    const int lane = tid & 63;
    const int w = tid >> 6;
    const int wm = w & 1, wn = w >> 1;
    const int lc = lane & 15, quad = lane >> 4;
    #pragma unroll
    for (int i = 0; i < 4; ++i)
        #pragma unroll
        for (int j = 0; j < 4; ++j) {
            int col = nbase + wn * 64 + j * 16 + lc;
            float bias = b2[e * D_MODEL + col];
            #pragma unroll
            for (int r = 0; r < 4; ++r) {
                int rloc = mloc + wm * 64 + i * 16 + quad * 4 + r;
                if (rloc < rows)
                    eo[(size_t)(base + rloc) * D_MODEL + col] = acc[i][j][r] + bias;
            }
        }
}

// ---------------- weighted combine ------------------------------------------

__global__ __launch_bounds__(256) void combine_kernel(
    const float* __restrict__ eo, const int* __restrict__ ainv,
    const float* __restrict__ top_p, float* __restrict__ out) {
    int t = blockIdx.x;
    int s0 = ainv[2 * t], s1 = ainv[2 * t + 1];
    float p0 = top_p[2 * t], p1 = top_p[2 * t + 1];
    int c = threadIdx.x * 4;
    f32x4 a = *(const f32x4*)(eo + (size_t)s0 * D_MODEL + c);
    f32x4 b = *(const f32x4*)(eo + (size_t)s1 * D_MODEL + c);
    f32x4 o;
    #pragma unroll
    for (int k = 0; k < 4; ++k) o[k] = a[k] * p0 + b[k] * p1;
    *(f32x4*)(out + (size_t)t * D_MODEL + c) = o;
}

// ---------------- launch ----------------------------------------------------

extern "C" void kernel_launch(void* const* d_in, const int* in_sizes, int n_in,
                              void* d_out, int out_size, void* d_ws, size_t ws_size,
                              hipStream_t stream) {
    const float* x     = (const float*)d_in[0];
    const float* r1w   = (const float*)d_in[1];
    const float* r1b   = (const float*)d_in[2];
    const float* lng   = (const float*)d_in[3];
    const float* lnb   = (const float*)d_in[4];
    const float* r2w   = (const float*)d_in[5];
    const float* r2b   = (const float*)d_in[6];
    const float* temp  = (const float*)d_in[7];
    const float* rbias = (const float*)d_in[8];
    const float* W1    = (const float*)d_in[9];
    const float* b1    = (const float*)d_in[10];
    const float* W2    = (const float*)d_in[11];
    const float* b2    = (const float*)d_in[12];
    float* out = (float*)d_out;

    char* ws = (char*)d_ws;
    size_t off = 0;
    auto alloc = [&](size_t bytes) -> void* {
        void* p = ws + off;
        off = (off + bytes + 255) & ~(size_t)255;
        return p;
    };
    bf16*  xh    = (bf16*)alloc((size_t)N_TOK * D_MODEL * 2);
    bf16*  xl    = (bf16*)alloc((size_t)N_TOK * D_MODEL * 2);
    bf16*  r1wTh = (bf16*)alloc((size_t)H_R * D_MODEL * 2);
    bf16*  r1wTl = (bf16*)alloc((size_t)H_R * D_MODEL * 2);
    bf16*  W1T   = (bf16*)alloc((size_t)N_EXP * F_FF * D_MODEL * 2);
    bf16*  W2T   = (bf16*)alloc((size_t)N_EXP * D_MODEL * F_FF * 2);
    float* hp0   = (float*)alloc((size_t)N_TOK * H_R * 4);
    int*   top_i = (int*)alloc((size_t)N_TOK * 2 * 4);
    float* top_p = (float*)alloc((size_t)N_TOK * 2 * 4);
    int*   meta  = (int*)alloc(256);
    int*   flags = (int*)alloc(FLAG_CAP * 4);
    int*   atok  = (int*)alloc((size_t)2 * N_TOK * 4);
    int*   ainv  = (int*)alloc((size_t)2 * N_TOK * 4);
    bf16*  actb  = (bf16*)alloc((size_t)2 * N_TOK * F_FF * 2);
    float* eo    = (float*)alloc((size_t)2 * N_TOK * D_MODEL * 4);
    float* hp1 = (float*)actb;
    float* hp2 = (float*)((char*)actb + (size_t)N_TOK * H_R * 4);
    (void)ws_size; (void)n_in; (void)in_sizes;

    hipMemsetAsync(meta, 0, 256, stream);

    convert_x_split<<<(N_TOK * D_MODEL) / (256 * 8), 256, 0, stream>>>(x, xh, xl);
    transpose_split<<<dim3(H_R / 32, D_MODEL / 32, 1), 256, 0, stream>>>(
        r1w, r1wTh, r1wTl, D_MODEL, H_R);
    transpose_bf16_64<<<dim3(F_FF / 64, D_MODEL / 64, N_EXP), 256, 0, stream>>>(
        W1, W1T, D_MODEL, F_FF);
    transpose_bf16_64<<<dim3(D_MODEL / 64, F_FF / 64, N_EXP), 256, 0, stream>>>(
        W2, W2T, F_FF, D_MODEL);

    router_gemm1_3<<<dim3(H_R / 128, N_TOK / 128, 3), 256, 0, stream>>>(
        xh, xl, r1wTh, r1wTl, hp0, hp1, hp2);
    ln_router2<<<N_TOK / 4, 256, 0, stream>>>(
        hp0, hp1, hp2, r1b, lng, lnb, r2w, r2b, temp, rbias, top_i, top_p, flags, meta);
    router_rescue<<<FLAG_CAP, 256, 0, stream>>>(
        x, r1w, r1b, lng, lnb, r2w, r2b, temp, rbias, flags, meta, top_i, top_p);
    route_pack<<<1, RP_T, 0, stream>>>(top_i, meta, atok, ainv);

    expert_gemm1<<<dim3(F_FF / 128, N_TOK / 128, N_EXP), 256, 0, stream>>>(
        xh, W1T, b1, meta, atok, actb);
    expert_gemm2<<<dim3(D_MODEL / 128, N_TOK / 128, N_EXP), 256, 0, stream>>>(
        actb, W2T, b2, meta, eo);
    combine_kernel<<<N_TOK, 256, 0, stream>>>(eo, ainv, top_p, out);
}